// Round 5
// baseline (26.603 us; speedup 1.0000x reference)
//
#include <hip/hip_runtime.h>

#define BB 8
#define SS 4096
#define DD 1024
#define TEMP 0.1f
#define PADV -100.0f
#define EPSV 1e-8f
#define BPB 128   // blocks per batch

// Single fused kernel. Every block recomputes its batch's compaction
// (labels are tiny and L2-hot) into LDS pos[rank] -> original position,
// then computes its assigned cosine pairs directly from LDS indices.
// Block 0 of each batch additionally writes the label output chunk and
// all -100 pads for both chunks (slot-disjoint from the valid writes).
__global__ __launch_bounds__(256) void fused_kernel(const float* __restrict__ x,
                                                    const int* __restrict__ labels,
                                                    float* __restrict__ out_cos,
                                                    float* __restrict__ out_lab) {
    int b    = blockIdx.y;
    int bid  = blockIdx.x;          // 0..BPB-1
    int t    = threadIdx.x;         // 0..255
    int lane = t & 63, wid = t >> 6;

    __shared__ int pos[SS];         // rank -> original position (first c entries)
    __shared__ int wsum[4];

    // ---- prologue: per-block compaction scan (redundant across blocks) ----
    const int* lab = labels + b * SS;
    int vals[16];
#pragma unroll
    for (int q = 0; q < 4; ++q) {
        int4 v = ((const int4*)lab)[t * 4 + q];
        vals[4*q+0] = v.x; vals[4*q+1] = v.y; vals[4*q+2] = v.z; vals[4*q+3] = v.w;
    }
    int mycnt = 0;
#pragma unroll
    for (int i = 0; i < 16; ++i) mycnt += (vals[i] != -100);

    int scan = mycnt;
#pragma unroll
    for (int off = 1; off < 64; off <<= 1) {
        int n = __shfl_up(scan, off, 64);
        if (lane >= off) scan += n;
    }
    if (lane == 63) wsum[wid] = scan;
    __syncthreads();

    int wbase = 0, c = 0;
#pragma unroll
    for (int w = 0; w < 4; ++w) {
        int s = wsum[w];
        wbase += (w < wid) ? s : 0;
        c += s;
    }
    int base = wbase + scan - mycnt;

    int o = base;
#pragma unroll
    for (int i = 0; i < 16; ++i) {
        if (vals[i] != -100) { pos[o] = t * 16 + i; ++o; }
    }

    if (bid == 0) {
        int o2 = base;
#pragma unroll
        for (int i = 0; i < 16; ++i) {
            if (vals[i] != -100) { out_lab[b * SS + o2] = (float)vals[i]; ++o2; }
        }
#pragma unroll
        for (int i = 0; i < 16; ++i) {
            int s = t * 16 + i;
            if (s >= c) { out_lab[b * SS + s] = PADV; out_cos[b * SS + s] = PADV; }
        }
    }
    __syncthreads();

    // ---- pair phase: 4 sweeps, 2 ranks per wave, 3 parallel vector loads ----
#pragma unroll
    for (int s = 0; s < SS / (BPB * 8); ++s) {
        int j0 = (s * BPB + bid) * 8 + wid * 2;
        if (j0 >= c) continue;

        int i0  = pos[j0];
        int jn0 = (j0 + 1 == c) ? 0 : (j0 + 1);
        int i1  = pos[jn0];
        bool p1 = (j0 + 1 < c);
        int jn1 = (j0 + 2 >= c) ? 0 : (j0 + 2);   // safe: never reads pos[>=c]
        int i2  = pos[jn1];

        const float* xb = x + (size_t)b * SS * DD + (size_t)lane * 4;
        const float* pa = xb + (size_t)i0 * DD;
        const float* pb = xb + (size_t)i1 * DD;
        const float* pc = xb + (size_t)i2 * DD;

        float4 A[4], B[4], C[4];
#pragma unroll
        for (int q = 0; q < 4; ++q) {
            A[q] = *(const float4*)(pa + q * 256);
            B[q] = *(const float4*)(pb + q * 256);
            C[q] = *(const float4*)(pc + q * 256);
        }

        float na = 0.f, nb = 0.f, nc = 0.f, dab = 0.f, dbc = 0.f;
#pragma unroll
        for (int q = 0; q < 4; ++q) {
            na  += A[q].x*A[q].x + A[q].y*A[q].y + A[q].z*A[q].z + A[q].w*A[q].w;
            nb  += B[q].x*B[q].x + B[q].y*B[q].y + B[q].z*B[q].z + B[q].w*B[q].w;
            nc  += C[q].x*C[q].x + C[q].y*C[q].y + C[q].z*C[q].z + C[q].w*C[q].w;
            dab += A[q].x*B[q].x + A[q].y*B[q].y + A[q].z*B[q].z + A[q].w*B[q].w;
            dbc += B[q].x*C[q].x + B[q].y*C[q].y + B[q].z*C[q].z + B[q].w*C[q].w;
        }
#pragma unroll
        for (int off = 32; off; off >>= 1) {
            na  += __shfl_xor(na,  off, 64);
            nb  += __shfl_xor(nb,  off, 64);
            nc  += __shfl_xor(nc,  off, 64);
            dab += __shfl_xor(dab, off, 64);
            dbc += __shfl_xor(dbc, off, 64);
        }

        if (lane == 0)
            out_cos[b * SS + j0] = dab / fmaxf(sqrtf(na) * sqrtf(nb), EPSV) / TEMP;
        if (lane == 1 && p1)
            out_cos[b * SS + j0 + 1] = dbc / fmaxf(sqrtf(nb) * sqrtf(nc), EPSV) / TEMP;
    }
}

extern "C" void kernel_launch(void* const* d_in, const int* in_sizes, int n_in,
                              void* d_out, int out_size, void* d_ws, size_t ws_size,
                              hipStream_t stream) {
    const float* seq    = (const float*)d_in[0];   // [B,S,D] f32
    const int*   labels = (const int*)d_in[1];     // [B,S] i32

    float* out_cos = (float*)d_out;                // [B,S]
    float* out_lab = (float*)d_out + BB * SS;      // [B,S] as floats

    dim3 grid(BPB, BB);                            // 1024 blocks, one dispatch
    fused_kernel<<<grid, 256, 0, stream>>>(seq, labels, out_cos, out_lab);
}

// Round 6
// 16.596 us; speedup vs baseline: 1.6029x; 1.6029x over previous
//
#include <hip/hip_runtime.h>

#define BB 8
#define SS 4096
#define DD 1024
#define TEMP 0.1f
#define PADV -100.0f
#define EPSV 1e-8f

// One block (1024 threads) per batch. Scan labels -> compacted positions in
// LDS, write label outputs + all pads for BOTH chunks, then emit pair
// descriptors desc[b][j] = (pos_j, pos_{(j+1)%c}) for j<c, (-1,-1) otherwise.
__global__ __launch_bounds__(1024) void compact_kernel(const int* __restrict__ labels,
                                                       int2* __restrict__ desc,
                                                       float* __restrict__ out_cos,
                                                       float* __restrict__ out_lab) {
    int b = blockIdx.x;
    int t = threadIdx.x;
    int lane = t & 63, wave = t >> 6;

    __shared__ int pos[SS];
    __shared__ int wsum[16];

    int4 v = ((const int4*)(labels + b * SS))[t];
    int vals[4] = {v.x, v.y, v.z, v.w};
    int mycnt = (vals[0] != -100) + (vals[1] != -100) + (vals[2] != -100) + (vals[3] != -100);

    int scan = mycnt;
#pragma unroll
    for (int off = 1; off < 64; off <<= 1) {
        int n = __shfl_up(scan, off, 64);
        if (lane >= off) scan += n;
    }
    if (lane == 63) wsum[wave] = scan;
    __syncthreads();

    int wbase = 0, c = 0;
#pragma unroll
    for (int w = 0; w < 16; ++w) {
        int s = wsum[w];
        wbase += (w < wave) ? s : 0;
        c += s;
    }
    int o = wbase + scan - mycnt;

#pragma unroll
    for (int i = 0; i < 4; ++i) {
        if (vals[i] != -100) {
            pos[o]              = 4 * t + i;
            out_lab[b * SS + o] = (float)vals[i];
            ++o;
        }
    }
    // pads for both output chunks (slots >= c; disjoint from valid writes)
#pragma unroll
    for (int i = 0; i < 4; ++i) {
        int s = 4 * t + i;
        if (s >= c) { out_lab[b * SS + s] = PADV; out_cos[b * SS + s] = PADV; }
    }
    __syncthreads();

    // pair descriptors, 4 per thread, two int4 stores
    int2 d[4];
#pragma unroll
    for (int i = 0; i < 4; ++i) {
        int j = 4 * t + i;
        if (j < c) {
            int jn = (j + 1 == c) ? 0 : (j + 1);
            d[i].x = pos[j];
            d[i].y = pos[jn];
        } else {
            d[i].x = -1;
            d[i].y = -1;
        }
    }
    int4* dp = (int4*)(desc + (size_t)b * SS + 4 * t);
    dp[0] = make_int4(d[0].x, d[0].y, d[1].x, d[1].y);
    dp[1] = make_int4(d[2].x, d[2].y, d[3].x, d[3].y);
}

// One WAVE per 2 consecutive ranks. Single int4 descriptor load (j0 even ->
// 16B aligned, covers both pairs: (i0,i1,i1,i2)), then 3 parallel vector
// loads. Dependent-load chain: desc -> vectors (1 level, was cnt->idx->vec).
__global__ __launch_bounds__(256) void cos_kernel(const float* __restrict__ x,
                                                  const int2* __restrict__ desc,
                                                  float* __restrict__ out_cos) {
    int b    = blockIdx.y;
    int lane = threadIdx.x & 63;
    int wid  = threadIdx.x >> 6;
    int j0   = (blockIdx.x * 4 + wid) * 2;

    int4 D = *(const int4*)(desc + (size_t)b * SS + j0);
    if (D.x < 0) return;                     // pads already written by compact
    bool p1 = (D.z >= 0);
    int i0 = D.x, i1 = D.y;
    int i2 = p1 ? D.w : D.y;                 // keep pointer valid when !p1

    const float* xb = x + (size_t)b * SS * DD + (size_t)lane * 4;
    const float* pa = xb + (size_t)i0 * DD;
    const float* pb = xb + (size_t)i1 * DD;
    const float* pc = xb + (size_t)i2 * DD;

    float4 A[4], B[4], C[4];
#pragma unroll
    for (int q = 0; q < 4; ++q) {
        A[q] = *(const float4*)(pa + q * 256);
        B[q] = *(const float4*)(pb + q * 256);
        C[q] = *(const float4*)(pc + q * 256);
    }

    float na = 0.f, nb = 0.f, nc = 0.f, dab = 0.f, dbc = 0.f;
#pragma unroll
    for (int q = 0; q < 4; ++q) {
        na  += A[q].x*A[q].x + A[q].y*A[q].y + A[q].z*A[q].z + A[q].w*A[q].w;
        nb  += B[q].x*B[q].x + B[q].y*B[q].y + B[q].z*B[q].z + B[q].w*B[q].w;
        nc  += C[q].x*C[q].x + C[q].y*C[q].y + C[q].z*C[q].z + C[q].w*C[q].w;
        dab += A[q].x*B[q].x + A[q].y*B[q].y + A[q].z*B[q].z + A[q].w*B[q].w;
        dbc += B[q].x*C[q].x + B[q].y*C[q].y + B[q].z*C[q].z + B[q].w*C[q].w;
    }
#pragma unroll
    for (int off = 32; off; off >>= 1) {
        na  += __shfl_xor(na,  off, 64);
        nb  += __shfl_xor(nb,  off, 64);
        nc  += __shfl_xor(nc,  off, 64);
        dab += __shfl_xor(dab, off, 64);
        dbc += __shfl_xor(dbc, off, 64);
    }

    if (lane == 0) {
        float r0 = dab / fmaxf(sqrtf(na) * sqrtf(nb), EPSV) / TEMP;
        float* op = out_cos + b * SS + j0;
        if (p1) {
            float r1 = dbc / fmaxf(sqrtf(nb) * sqrtf(nc), EPSV) / TEMP;
            *(float2*)op = make_float2(r0, r1);
        } else {
            *op = r0;
        }
    }
}

extern "C" void kernel_launch(void* const* d_in, const int* in_sizes, int n_in,
                              void* d_out, int out_size, void* d_ws, size_t ws_size,
                              hipStream_t stream) {
    const float* seq    = (const float*)d_in[0];   // [B,S,D] f32
    const int*   labels = (const int*)d_in[1];     // [B,S] i32

    float* out_cos = (float*)d_out;                // [B,S]
    float* out_lab = (float*)d_out + BB * SS;      // [B,S] as floats

    int2* desc = (int2*)d_ws;                      // B*S int2 descriptors

    compact_kernel<<<BB, 1024, 0, stream>>>(labels, desc, out_cos, out_lab);

    dim3 grid(SS / 8, BB);                         // 4 waves/block, 2 ranks/wave
    cos_kernel<<<grid, 256, 0, stream>>>(seq, desc, out_cos);
}